// Round 6
// baseline (520.436 us; speedup 1.0000x reference)
//
#include <hip/hip_runtime.h>
#include <hip/hip_bf16.h>

// Problem constants
#define B_    2
#define S_    2048
#define E_    2048
#define H_    16
#define HKV_  4
#define D_    128
#define NTOK  4096      // B_*S_
#define KVDIM 512       // HKV_*D_

typedef __bf16 bf16x8 __attribute__((ext_vector_type(8)));
typedef __bf16 bf16x4 __attribute__((ext_vector_type(4)));
typedef float  f32x4  __attribute__((ext_vector_type(4)));

__device__ __forceinline__ void async_copy16(const void* g, void* l) {
  // 16B per lane; LDS dest = wave-uniform base + lane*16 (m104/m108 semantics)
  __builtin_amdgcn_global_load_lds(
      (const __attribute__((address_space(1))) unsigned int*)g,
      (__attribute__((address_space(3))) unsigned int*)l, 16, 0, 0);
}

// ---------------------------------------------------------------------------
// Fused: 4-weight transpose+convert (z=0..3) + query fp32->bf16 copy (z=4).
// ---------------------------------------------------------------------------
__global__ __launch_bounds__(256) void transpose_all(
    const float* __restrict__ Wq, const float* __restrict__ Wk,
    const float* __restrict__ Wv, const float* __restrict__ Wo,
    __bf16* __restrict__ WTq, __bf16* __restrict__ WTk,
    __bf16* __restrict__ WTv, __bf16* __restrict__ WoT,
    const float* __restrict__ query, __bf16* __restrict__ qb) {
  if (blockIdx.z == 4) {
    // convert slice: 2048 xy-blocks x 256 thr x 16 elems = 8.39M = NTOK*E_
    const size_t i =
        (((size_t)blockIdx.y * 64 + blockIdx.x) * 256 + threadIdx.x) * 16;
    const f32x4 a0 = *(const f32x4*)(query + i);
    const f32x4 a1 = *(const f32x4*)(query + i + 4);
    const f32x4 a2 = *(const f32x4*)(query + i + 8);
    const f32x4 a3 = *(const f32x4*)(query + i + 12);
    bf16x8 v0, v1;
#pragma unroll
    for (int j = 0; j < 4; ++j) {
      v0[j] = (__bf16)a0[j]; v0[4 + j] = (__bf16)a1[j];
      v1[j] = (__bf16)a2[j]; v1[4 + j] = (__bf16)a3[j];
    }
    *(bf16x8*)(qb + i) = v0;
    *(bf16x8*)(qb + i + 8) = v1;
    return;
  }
  const float* in;
  __bf16* out;
  int C;
  switch (blockIdx.z) {
    case 0:  in = Wq; out = WTq; C = E_;   break;
    case 1:  in = Wk; out = WTk; C = KVDIM; break;
    case 2:  in = Wv; out = WTv; C = KVDIM; break;
    default: in = Wo; out = WoT; C = E_;   break;
  }
  const int c0 = blockIdx.x * 32;
  if (c0 >= C) return;  // uniform early-exit (idle z=1/2 blocks)
  const int r0 = blockIdx.y * 64;
  __shared__ float t[32][65];            // t[c][r]
  const int lr = threadIdx.x >> 2;       // 0..63 input row
  const int lc = (threadIdx.x & 3) * 8;  // 0,8,16,24 input col
  const float* ip = in + (size_t)(r0 + lr) * C + c0 + lc;
  const f32x4 a0 = *(const f32x4*)ip;
  const f32x4 a1 = *(const f32x4*)(ip + 4);
#pragma unroll
  for (int j = 0; j < 4; ++j) t[lc + j][lr] = a0[j];
#pragma unroll
  for (int j = 0; j < 4; ++j) t[lc + 4 + j][lr] = a1[j];
  __syncthreads();
  const int oc = threadIdx.x >> 3;        // 0..31 output row (c)
  const int orr = (threadIdx.x & 7) * 8;  // 0..56 output col (r)
  bf16x8 v;
#pragma unroll
  for (int j = 0; j < 8; ++j) v[j] = (__bf16)t[oc][orr + j];
  *(bf16x8*)(out + (size_t)(c0 + oc) * E_ + r0 + orr) = v;  // 16B coalesced
}

// ---------------------------------------------------------------------------
// Fine-grained pipelined GEMM (frozen structure; round 6 adds XCD swizzle:
// 256 blocks, XCD x gets n-panel x entirely -> 1MB B-panel resident per-L2).
// C = A(bf16,[M][K]) @ Bt(bf16,[N][K])^T. BM=128, BN=256, BK=64, 512 thr.
// ---------------------------------------------------------------------------
__global__ __launch_bounds__(512, 1) void gemm_pipe(
    const __bf16* __restrict__ A, const __bf16* __restrict__ Bt,
    float* __restrict__ Cf, __bf16* __restrict__ Cb, int M, int N, int K,
    int epi) {
  // buf layout: [2][A 128*64 | B 256*64] bf16 = 2 * 24576 elems = 96 KB
  __shared__ __align__(16) __bf16 lds[2 * 24576];

  // XCD-aware swizzle (T1): lin%8 = XCD; give each XCD one contiguous n-panel
  const int lin = blockIdx.y * gridDim.x + blockIdx.x;  // 0..255
  const int swz = (lin & 7) * 32 + (lin >> 3);
  const int n0 = (swz >> 5) * 256;
  const int m0 = (swz & 31) * 128;
  const int tid = threadIdx.x;
  const int w = tid >> 6;
  const int lane = tid & 63;
  const int quad = lane >> 4;
  const int l16 = lane & 15;
  const int wm = w >> 2;      // 0..1
  const int wn = w & 3;       // 0..3
  const int lr = lane >> 3;   // 0..7 (staging row within 8-row group)
  const int ls = lane & 7;    // staging 16B slot

  const __bf16* pa[2];
  const __bf16* pb[4];
#pragma unroll
  for (int r = 0; r < 2; ++r) {
    const int row = r * 64 + w * 8 + lr;
    pa[r] = A + (size_t)(m0 + row) * K + ((ls ^ (row & 7)) * 8);
  }
#pragma unroll
  for (int r = 0; r < 4; ++r) {
    const int row = r * 64 + w * 8 + lr;
    pb[r] = Bt + (size_t)(n0 + row) * K + ((ls ^ (row & 7)) * 8);
  }

  auto stageA = [&](int bufi) {
    __bf16* base = lds + bufi * 24576;
#pragma unroll
    for (int r = 0; r < 2; ++r) {
      async_copy16(pa[r], base + (size_t)(r * 64 + w * 8) * 64);
      pa[r] += 64;
    }
  };
  auto stageB = [&](int bufi) {
    __bf16* base = lds + bufi * 24576 + 8192;
#pragma unroll
    for (int r = 0; r < 4; ++r) {
      async_copy16(pb[r], base + (size_t)(r * 64 + w * 8) * 64);
      pb[r] += 64;
    }
  };

  f32x4 acc[4][4] = {};
  const int NT = K >> 6;
  const int xr = l16 & 7;

  stageA(0);            // 2 loads
  stageB(0);            // 4 loads
  stageB(1);            // 4 loads
  asm volatile("s_waitcnt vmcnt(4)" ::: "memory");  // tile0 landed
  __builtin_amdgcn_s_barrier();

  for (int t = 0; t < NT; ++t) {
    const __bf16* lA = lds + (t & 1) * 24576;
    const __bf16* lB = lA + 8192;

    // ======== P0: f-half 0 ========
    bf16x8 af[2][2], bfr[4][2];
#pragma unroll
    for (int f = 0; f < 2; ++f) {
      const int rowb = (wm * 64 + f * 16 + l16) * 64;
#pragma unroll
      for (int ks = 0; ks < 2; ++ks)
        af[f][ks] = *(const bf16x8*)&lA[rowb + (((ks * 4 + quad) ^ xr) * 8)];
    }
#pragma unroll
    for (int g = 0; g < 4; ++g) {
      const int rowb = (wn * 64 + g * 16 + l16) * 64;
#pragma unroll
      for (int ks = 0; ks < 2; ++ks)
        bfr[g][ks] = *(const bf16x8*)&lB[rowb + (((ks * 4 + quad) ^ xr) * 8)];
    }
    if (t + 1 < NT) stageA((t + 1) & 1);  // A region of other buf is free
    __builtin_amdgcn_s_barrier();
    asm volatile("s_waitcnt lgkmcnt(0)" ::: "memory");
    __builtin_amdgcn_sched_barrier(0);
    __builtin_amdgcn_s_setprio(1);
#pragma unroll
    for (int f = 0; f < 2; ++f)
#pragma unroll
      for (int g = 0; g < 4; ++g) {
        acc[f][g] = __builtin_amdgcn_mfma_f32_16x16x32_bf16(af[f][0], bfr[g][0],
                                                            acc[f][g], 0, 0, 0);
        acc[f][g] = __builtin_amdgcn_mfma_f32_16x16x32_bf16(af[f][1], bfr[g][1],
                                                            acc[f][g], 0, 0, 0);
      }
    __builtin_amdgcn_s_setprio(0);
    __builtin_amdgcn_s_barrier();  // closes B region of buf[t&1]

    // ======== P1: f-half 1 ========
    bf16x8 ah[2][2];
#pragma unroll
    for (int f = 0; f < 2; ++f) {
      const int rowb = (wm * 64 + (f + 2) * 16 + l16) * 64;
#pragma unroll
      for (int ks = 0; ks < 2; ++ks)
        ah[f][ks] = *(const bf16x8*)&lA[rowb + (((ks * 4 + quad) ^ xr) * 8)];
    }
    if (t + 2 < NT) stageB(t & 1);  // B region of buf[t&1] freed by P0 close
    __builtin_amdgcn_s_barrier();
    asm volatile("s_waitcnt lgkmcnt(0)" ::: "memory");
    __builtin_amdgcn_sched_barrier(0);
    __builtin_amdgcn_s_setprio(1);
#pragma unroll
    for (int f = 0; f < 2; ++f)
#pragma unroll
      for (int g = 0; g < 4; ++g) {
        acc[f + 2][g] = __builtin_amdgcn_mfma_f32_16x16x32_bf16(
            ah[f][0], bfr[g][0], acc[f + 2][g], 0, 0, 0);
        acc[f + 2][g] = __builtin_amdgcn_mfma_f32_16x16x32_bf16(
            ah[f][1], bfr[g][1], acc[f + 2][g], 0, 0, 0);
      }
    __builtin_amdgcn_s_setprio(0);

    if (t + 2 < NT) {
      asm volatile("s_waitcnt vmcnt(4)" ::: "memory");
      __builtin_amdgcn_s_barrier();
    } else if (t + 1 < NT) {
      asm volatile("s_waitcnt vmcnt(0)" ::: "memory");
      __builtin_amdgcn_s_barrier();
    }
  }

  // C/D layout: col = lane&15 (n), row = quad*4 + reg (m). [m89/m91]
#pragma unroll
  for (int f = 0; f < 4; ++f) {
#pragma unroll
    for (int g = 0; g < 4; ++g) {
#pragma unroll
      for (int r = 0; r < 4; ++r) {
        const int m = m0 + wm * 64 + f * 16 + quad * 4 + r;
        const int n = n0 + wn * 64 + g * 16 + l16;
        if (epi == 0) Cf[(size_t)m * N + n] = acc[f][g][r];
        else          Cb[(size_t)m * N + n] = (__bf16)acc[f][g][r];
      }
    }
  }
}

// ---------------------------------------------------------------------------
// K/V projection (m97-style kernel, fp32 A converted during staging; frozen).
// ---------------------------------------------------------------------------
__global__ __launch_bounds__(256, 2) void gemm_kv(
    const float* __restrict__ key, const float* __restrict__ value,
    const __bf16* __restrict__ WTk, const __bf16* __restrict__ WTv,
    __bf16* __restrict__ Kp, __bf16* __restrict__ Vt) {
  __shared__ __align__(16) __bf16 As[128 * 32];
  __shared__ __align__(16) __bf16 Bs[128 * 32];

  const int bx = blockIdx.x;  // 0..7
  const float* A;
  const __bf16* Bt;
  int n0, epi;
  if (bx < 4) { A = key;   Bt = WTk; n0 = bx * 128;       epi = 0; }
  else        { A = value; Bt = WTv; n0 = (bx - 4) * 128; epi = 1; }
  const int m0 = blockIdx.y * 128;
  const int K = E_;
  const int N = KVDIM;

  const int tid = threadIdx.x;
  const int w = tid >> 6;
  const int lane = tid & 63;
  const int quad = lane >> 4;
  const int l16 = lane & 15;
  const int wr = w >> 1, wc = w & 1;
  const int brow = lane >> 2;
  const int bcol = (lane & 3) * 8;
  const int arow = lane >> 2;
  const int acol = (lane & 3) * 8;

  f32x4 acc[4][4] = {};

  for (int k0 = 0; k0 < K; k0 += 32) {
    __syncthreads();
#pragma unroll
    for (int c = 0; c < 2; ++c) {
      const int chunk = w * 2 + c;
      const int row = chunk * 16 + brow;
      async_copy16(Bt + (size_t)(n0 + row) * K + k0 + bcol, &Bs[chunk * 512]);
    }
#pragma unroll
    for (int s = 0; s < 2; ++s) {
      const int row = w * 32 + s * 16 + arow;
      const float* src = A + (size_t)(m0 + row) * K + k0 + acol;
      const f32x4 a0 = *(const f32x4*)src;
      const f32x4 a1 = *(const f32x4*)(src + 4);
      bf16x8 v;
#pragma unroll
      for (int j = 0; j < 4; ++j) { v[j] = (__bf16)a0[j]; v[4 + j] = (__bf16)a1[j]; }
      *(bf16x8*)&As[row * 32 + acol] = v;
    }
    __syncthreads();
    bf16x8 af[4], bfr[4];
#pragma unroll
    for (int i = 0; i < 4; ++i)
      af[i] = *(const bf16x8*)&As[(wr * 64 + i * 16 + l16) * 32 + quad * 8];
#pragma unroll
    for (int j = 0; j < 4; ++j)
      bfr[j] = *(const bf16x8*)&Bs[(wc * 64 + j * 16 + l16) * 32 + quad * 8];
#pragma unroll
    for (int i = 0; i < 4; ++i)
#pragma unroll
      for (int j = 0; j < 4; ++j)
        acc[i][j] = __builtin_amdgcn_mfma_f32_16x16x32_bf16(af[i], bfr[j],
                                                            acc[i][j], 0, 0, 0);
  }

#pragma unroll
  for (int i = 0; i < 4; ++i) {
#pragma unroll
    for (int j = 0; j < 4; ++j) {
#pragma unroll
      for (int r = 0; r < 4; ++r) {
        const int m = m0 + wr * 64 + i * 16 + quad * 4 + r;
        const int n = n0 + wc * 64 + j * 16 + l16;
        if (epi == 0) {
          Kp[(size_t)m * N + n] = (__bf16)acc[i][j][r];
        } else {
          const int b = m >> 11, s = m & (S_ - 1);
          Vt[((size_t)((b * HKV_ + (n >> 7)) * D_ + (n & (D_ - 1)))) * S_ + s] =
              (__bf16)acc[i][j][r];
        }
      }
    }
  }
}

// ---------------------------------------------------------------------------
// Flash attention, round 6: SWAPPED QK^T + in-register P (no P_lds).
// sT = mfma(A=K, B=Q): D[row=quad*4+r -> kv = n*16+quad*4+r][col=l16 -> qrow].
// PV A-frag needs P[qrow=l16][kv=ks2*32+quadPV*8+j]: same l16, only quads
// differ -> quad-exchange via shfl_xor(16/32) of bf16x4-packed values.
// Derivation (verified per-quad):
//   pb[n] = bf16x4(P at kv = n*16 + quad*4 + {0..3}), qrow = l16.
//   pair_n = (even-quad vals, odd-quad vals) via shfl_xor16.
//   lane group g = quad>>1 holds pairs of quads (2g, 2g+1).
//   target quadPV needs group quadPV&1, register n = 2ks2 + (quadPV>>1):
//   send pair_{g^1} through shfl_xor32, keep pair_g; select by
//   sw = (quad>>1)^(quad&1).
// LDS 54.3 -> 35.8 KB; launch_bounds(256,3) -> 12 waves/CU (was 8).
// ---------------------------------------------------------------------------
__global__ __launch_bounds__(256, 3) void attn_kernel(
    const __bf16* __restrict__ Q, const __bf16* __restrict__ Kp,
    const __bf16* __restrict__ Vt, const float* __restrict__ mask,
    __bf16* __restrict__ Oa) {
  __shared__ __align__(16) __bf16 K_lds[64][136];
  __shared__ __align__(16) __bf16 V_lds[128][72];

  const int tid = threadIdx.x;
  const int w = tid >> 6, lane = tid & 63, quad = lane >> 4, l16 = lane & 15;
  const int bh = blockIdx.y;
  const int b = bh >> 4, h = bh & 15, hkv = h >> 2;
  const int q0 = blockIdx.x * 128 + w * 32;

  const __bf16* qbase = Q + (size_t)(b * S_ + q0) * E_ + h * D_;
  bf16x8 qf[2][4];
#pragma unroll
  for (int m = 0; m < 2; ++m)
#pragma unroll
    for (int ks = 0; ks < 4; ++ks)
      qf[m][ks] = *(const bf16x8*)(qbase + (size_t)(m * 16 + l16) * E_ +
                                   ks * 32 + quad * 8);

  const __bf16* kbase = Kp + (size_t)(b * S_) * KVDIM + hkv * D_;
  const __bf16* vbase = Vt + (size_t)((b * HKV_ + hkv) * D_) * S_;
  const float* mbase = mask + b * S_;

  f32x4 o[2][8] = {};
  float lsum[2] = {0.0f, 0.0f};
  const float scale = 0.08838834764831845f;  // 1/sqrt(128)
  const bool oddq = (quad & 1) != 0;
  const bool hig = (quad >> 1) != 0;
  const bool sw = hig != oddq;

  for (int kt = 0; kt < S_; kt += 64) {
    __syncthreads();
#pragma unroll
    for (int i = 0; i < 4; ++i) {
      const int r = w * 16 + i * 4 + (lane >> 4);
      bf16x8 kv = *(const bf16x8*)(kbase + (size_t)(kt + r) * KVDIM +
                                   (lane & 15) * 8);
      *(bf16x8*)&K_lds[r][(lane & 15) * 8] = kv;
    }
#pragma unroll
    for (int i = 0; i < 4; ++i) {
      const int r = w * 32 + i * 8 + (lane >> 3);
      bf16x8 vv = *(const bf16x8*)(vbase + (size_t)r * S_ + kt +
                                   (lane & 7) * 8);
      *(bf16x8*)&V_lds[r][(lane & 7) * 8] = vv;
    }
    __syncthreads();

    // bias per kv row: kv = n*16 + quad*4 + r  (f32x4 along r)
    f32x4 breg[4];
#pragma unroll
    for (int n = 0; n < 4; ++n)
      breg[n] = *(const f32x4*)(mbase + kt + n * 16 + quad * 4);

    uint2 pb[2][4];
#pragma unroll
    for (int m = 0; m < 2; ++m) {
      f32x4 st[4] = {};
      __builtin_amdgcn_s_setprio(1);
#pragma unroll
      for (int ks = 0; ks < 4; ++ks) {
#pragma unroll
        for (int n = 0; n < 4; ++n) {
          bf16x8 kf = *(const bf16x8*)&K_lds[n * 16 + l16][ks * 32 + quad * 8];
          st[n] = __builtin_amdgcn_mfma_f32_16x16x32_bf16(kf, qf[m][ks],
                                                          st[n], 0, 0, 0);
        }
      }
      __builtin_amdgcn_s_setprio(0);
#pragma unroll
      for (int n = 0; n < 4; ++n) {
        union { bf16x4 b; uint2 u; } t;
#pragma unroll
        for (int r = 0; r < 4; ++r) {
          const float p =
              __expf(st[n][r] * scale + (1.0f - breg[n][r]) * -1e9f);
          lsum[m] += p;
          t.b[r] = (__bf16)p;
        }
        pb[m][n] = t.u;
      }
    }

    // PV with in-register quad-exchange
    __builtin_amdgcn_s_setprio(1);
#pragma unroll
    for (int ks2 = 0; ks2 < 2; ++ks2) {
      bf16x8 pav[2];
#pragma unroll
      for (int m = 0; m < 2; ++m) {
        const uint2 plo = pb[m][2 * ks2];
        const uint2 phi = pb[m][2 * ks2 + 1];
        uint2 plo16, phi16;
        plo16.x = __shfl_xor((int)plo.x, 16);
        plo16.y = __shfl_xor((int)plo.y, 16);
        phi16.x = __shfl_xor((int)phi.x, 16);
        phi16.y = __shfl_xor((int)phi.y, 16);
        const uint2 p0l = oddq ? plo16 : plo;  // even-quad n0 vals
        const uint2 p0h = oddq ? plo : plo16;  // odd-quad n0 vals
        const uint2 p1l = oddq ? phi16 : phi;
        const uint2 p1h = oddq ? phi : phi16;
        uint2 zsl = hig ? p0l : p1l;  // pair_{g^1} outbound
        uint2 zsh = hig ? p0h : p1h;
        uint2 zl, zh;
        zl.x = __shfl_xor((int)zsl.x, 32);
        zl.y = __shfl_xor((int)zsl.y, 32);
        zh.x = __shfl_xor((int)zsh.x, 32);
        zh.y = __shfl_xor((int)zsh.y, 32);
        const uint2 kl = hig ? p1l : p0l;  // pair_g kept
        const uint2 kh = hig ? p1h : p0h;
        union { bf16x8 b; uint2 u[2]; } pa_u;
        pa_u.u[0] = sw ? zl : kl;  // k-slots j=0..3
        pa_u.u[1] = sw ? zh : kh;  // j=4..7
        pav[m] = pa_u.b;
      }
#pragma unroll
      for (int dt = 0; dt < 8; ++dt) {
        bf16x8 vf = *(const bf16x8*)&V_lds[dt * 16 + l16][ks2 * 32 + quad * 8];
        o[0][dt] = __builtin_amdgcn_mfma_f32_16x16x32_bf16(pav[0], vf,
                                                           o[0][dt], 0, 0, 0);
        o[1][dt] = __builtin_amdgcn_mfma_f32_16x16x32_bf16(pav[1], vf,
                                                           o[1][dt], 0, 0, 0);
      }
    }
    __builtin_amdgcn_s_setprio(0);
  }

  __bf16* obase = Oa + (size_t)(b * S_ + q0) * E_ + h * D_;
#pragma unroll
  for (int m = 0; m < 2; ++m) {
    // lsum[m] = per-lane partial for qrow = m*16 + l16; reduce across quads
    float tot = lsum[m];
    tot += __shfl_xor(tot, 16);
    tot += __shfl_xor(tot, 32);
#pragma unroll
    for (int r = 0; r < 4; ++r) {
      // row-sum for qrow = m*16 + quad*4 + r lives at lanes with l16=quad*4+r
      const float sr = __shfl(tot, (quad << 4) | (quad * 4 + r));
      const float inv = 1.0f / sr;
#pragma unroll
      for (int dt = 0; dt < 8; ++dt)
        obase[(size_t)(m * 16 + quad * 4 + r) * E_ + dt * 16 + l16] =
            (__bf16)(o[m][dt][r] * inv);
    }
  }
}

// ---------------------------------------------------------------------------
extern "C" void kernel_launch(void* const* d_in, const int* in_sizes, int n_in,
                              void* d_out, int out_size, void* d_ws,
                              size_t ws_size, hipStream_t stream) {
  const float* query = (const float*)d_in[0];
  const float* key   = (const float*)d_in[1];
  const float* value = (const float*)d_in[2];
  const float* mask  = (const float*)d_in[3];
  const float* Wq    = (const float*)d_in[4];
  const float* Wk    = (const float*)d_in[5];
  const float* Wv    = (const float*)d_in[6];
  const float* Wo    = (const float*)d_in[7];
  float* out = (float*)d_out;

  // Workspace 48 MB (known-safe), bf16 elements:
  //   Qp 16MB | Kp 4MB | Vt 4MB | WoT 8MB | WTq 8MB | WTk 2MB | WTv 2MB | sp 4MB
  // Attn (16MB) overlaps [WTq|WTk|WTv|spare] — consumed before attention runs.
  // qb (bf16 query, 16MB) lives in d_out (32MB fp32) — fully overwritten by
  // the final O-projection, consumed before it.
  __bf16* ws   = (__bf16*)d_ws;
  __bf16* Qp   = ws;                           // @ 0
  __bf16* Kp   = Qp + (size_t)NTOK * E_;       // @ 16MB
  __bf16* Vt   = Kp + (size_t)NTOK * KVDIM;    // @ 20MB
  __bf16* WoT  = Vt + (size_t)NTOK * KVDIM;    // @ 24MB
  __bf16* WTq  = WoT + (size_t)E_ * E_;        // @ 32MB
  __bf16* WTk  = WTq + (size_t)E_ * E_;        // @ 40MB
  __bf16* WTv  = WTk + (size_t)KVDIM * E_;     // @ 42MB
  __bf16* Attn = WTq;                          // @ 32MB (16MB, reuse)
  __bf16* qb   = (__bf16*)d_out;               // 16MB scratch in output buf

  // 1) weight transposes + query convert in one launch (z=4 = convert slice)
  transpose_all<<<dim3(64, 32, 5), 256, 0, stream>>>(Wq, Wk, Wv, Wo,
                                                     WTq, WTk, WTv, WoT,
                                                     query, qb);
  // 2) K/V projections (old structure, fp32 A), 8x32 = 256 blocks
  gemm_kv<<<dim3(8, 32), 256, 0, stream>>>(key, value, WTk, WTv, Kp, Vt);
  // 3) Q projection via pipelined GEMM: qb @ WTq -> Qp (bf16 epilogue)
  gemm_pipe<<<dim3(8, 32), 512, 0, stream>>>(
      qb, WTq, nullptr, Qp, NTOK, E_, E_, 1);
  // 4) attention -> Attn (clobbers WTq/k/v, already consumed)
  attn_kernel<<<dim3(S_ / 128, B_ * H_), 256, 0, stream>>>(Qp, Kp, Vt, mask,
                                                           Attn);
  // 5) output projection via pipelined GEMM (fp32 epilogue straight to d_out)
  gemm_pipe<<<dim3(8, 32), 512, 0, stream>>>(
      Attn, WoT, out, nullptr, NTOK, E_, E_, 0);
}

// Round 7
// 381.176 us; speedup vs baseline: 1.3653x; 1.3653x over previous
//
#include <hip/hip_runtime.h>
#include <hip/hip_bf16.h>

// Problem constants
#define B_    2
#define S_    2048
#define E_    2048
#define H_    16
#define HKV_  4
#define D_    128
#define NTOK  4096      // B_*S_
#define KVDIM 512       // HKV_*D_

typedef __bf16 bf16x8 __attribute__((ext_vector_type(8)));
typedef __bf16 bf16x4 __attribute__((ext_vector_type(4)));
typedef float  f32x4  __attribute__((ext_vector_type(4)));

__device__ __forceinline__ void async_copy16(const void* g, void* l) {
  // 16B per lane; LDS dest = wave-uniform base + lane*16 (m104/m108 semantics)
  __builtin_amdgcn_global_load_lds(
      (const __attribute__((address_space(1))) unsigned int*)g,
      (__attribute__((address_space(3))) unsigned int*)l, 16, 0, 0);
}

// ---------------------------------------------------------------------------
// Fused prep kernel: z=0..3 weight transpose+convert (fp32 [R][C]->bf16
// [C][R]); z=4..6 fp32->bf16 convert of query/key/value (16 elems/thread).
// ---------------------------------------------------------------------------
__global__ __launch_bounds__(256) void transpose_all(
    const float* __restrict__ Wq, const float* __restrict__ Wk,
    const float* __restrict__ Wv, const float* __restrict__ Wo,
    __bf16* __restrict__ WTq, __bf16* __restrict__ WTk,
    __bf16* __restrict__ WTv, __bf16* __restrict__ WoT,
    const float* __restrict__ query, const float* __restrict__ key,
    const float* __restrict__ value, __bf16* __restrict__ qb,
    __bf16* __restrict__ kb, __bf16* __restrict__ vb) {
  if (blockIdx.z >= 4) {
    const float* src;
    __bf16* dst;
    switch (blockIdx.z) {
      case 4:  src = query; dst = qb; break;
      case 5:  src = key;   dst = kb; break;
      default: src = value; dst = vb; break;
    }
    // 2048 xy-blocks x 256 thr x 16 elems = 8.39M = NTOK*E_
    const size_t i =
        (((size_t)blockIdx.y * 64 + blockIdx.x) * 256 + threadIdx.x) * 16;
    const f32x4 a0 = *(const f32x4*)(src + i);
    const f32x4 a1 = *(const f32x4*)(src + i + 4);
    const f32x4 a2 = *(const f32x4*)(src + i + 8);
    const f32x4 a3 = *(const f32x4*)(src + i + 12);
    bf16x8 v0, v1;
#pragma unroll
    for (int j = 0; j < 4; ++j) {
      v0[j] = (__bf16)a0[j]; v0[4 + j] = (__bf16)a1[j];
      v1[j] = (__bf16)a2[j]; v1[4 + j] = (__bf16)a3[j];
    }
    *(bf16x8*)(dst + i) = v0;
    *(bf16x8*)(dst + i + 8) = v1;
    return;
  }
  const float* in;
  __bf16* out;
  int C;
  switch (blockIdx.z) {
    case 0:  in = Wq; out = WTq; C = E_;   break;
    case 1:  in = Wk; out = WTk; C = KVDIM; break;
    case 2:  in = Wv; out = WTv; C = KVDIM; break;
    default: in = Wo; out = WoT; C = E_;   break;
  }
  const int c0 = blockIdx.x * 32;
  if (c0 >= C) return;  // uniform early-exit (idle z=1/2 blocks)
  const int r0 = blockIdx.y * 64;
  __shared__ float t[32][65];            // t[c][r]
  const int lr = threadIdx.x >> 2;       // 0..63 input row
  const int lc = (threadIdx.x & 3) * 8;  // 0,8,16,24 input col
  const float* ip = in + (size_t)(r0 + lr) * C + c0 + lc;
  const f32x4 a0 = *(const f32x4*)ip;
  const f32x4 a1 = *(const f32x4*)(ip + 4);
#pragma unroll
  for (int j = 0; j < 4; ++j) t[lc + j][lr] = a0[j];
#pragma unroll
  for (int j = 0; j < 4; ++j) t[lc + 4 + j][lr] = a1[j];
  __syncthreads();
  const int oc = threadIdx.x >> 3;        // 0..31 output row (c)
  const int orr = (threadIdx.x & 7) * 8;  // 0..56 output col (r)
  bf16x8 v;
#pragma unroll
  for (int j = 0; j < 8; ++j) v[j] = (__bf16)t[oc][orr + j];
  *(bf16x8*)(out + (size_t)(c0 + oc) * E_ + r0 + orr) = v;  // 16B coalesced
}

// ---------------------------------------------------------------------------
// Fine-grained pipelined GEMM. Round 7: 2D XCD partition (fetch-locality
// fix — round-0 PMC showed 297 MB FETCH = cross-XCD A re-fetch at 2.5 TB/s
// dominating). 1D grid of 256; XCD = id&7 (dispatch round-robin model):
//   XCD -> (m-quarter = xcd>>1, n-half = xcd&1); per-XCD working set =
//   A 4MB + B 4MB (vs full-A 16MB re-fetch per XCD before).
// C = A(bf16,[M][K]) @ Bt(bf16,[N][K])^T. BM=128, BN=256, BK=64, 512 thr.
// ---------------------------------------------------------------------------
__global__ __launch_bounds__(512, 1) void gemm_pipe(
    const __bf16* __restrict__ A, const __bf16* __restrict__ Bt,
    float* __restrict__ Cf, __bf16* __restrict__ Cb, int M, int N, int K,
    int epi) {
  // buf layout: [2][A 128*64 | B 256*64] bf16 = 2 * 24576 elems = 96 KB
  __shared__ __align__(16) __bf16 lds[2 * 24576];

  const int bxl = blockIdx.x;        // 0..255
  const int xcd = bxl & 7;
  const int sub = bxl >> 3;          // 0..31
  const int m0 = ((xcd >> 1) * 8 + (sub >> 2)) * 128;  // 32 m-blocks
  const int n0 = ((xcd & 1) * 4 + (sub & 3)) * 256;    // 8 n-blocks
  const int tid = threadIdx.x;
  const int w = tid >> 6;
  const int lane = tid & 63;
  const int quad = lane >> 4;
  const int l16 = lane & 15;
  const int wm = w >> 2;      // 0..1
  const int wn = w & 3;       // 0..3
  const int lr = lane >> 3;   // 0..7 (staging row within 8-row group)
  const int ls = lane & 7;    // staging 16B slot

  const __bf16* pa[2];
  const __bf16* pb[4];
#pragma unroll
  for (int r = 0; r < 2; ++r) {
    const int row = r * 64 + w * 8 + lr;
    pa[r] = A + (size_t)(m0 + row) * K + ((ls ^ (row & 7)) * 8);
  }
#pragma unroll
  for (int r = 0; r < 4; ++r) {
    const int row = r * 64 + w * 8 + lr;
    pb[r] = Bt + (size_t)(n0 + row) * K + ((ls ^ (row & 7)) * 8);
  }

  auto stageA = [&](int bufi) {
    __bf16* base = lds + bufi * 24576;
#pragma unroll
    for (int r = 0; r < 2; ++r) {
      async_copy16(pa[r], base + (size_t)(r * 64 + w * 8) * 64);
      pa[r] += 64;
    }
  };
  auto stageB = [&](int bufi) {
    __bf16* base = lds + bufi * 24576 + 8192;
#pragma unroll
    for (int r = 0; r < 4; ++r) {
      async_copy16(pb[r], base + (size_t)(r * 64 + w * 8) * 64);
      pb[r] += 64;
    }
  };

  f32x4 acc[4][4] = {};
  const int NT = K >> 6;
  const int xr = l16 & 7;

  stageA(0);            // 2 loads
  stageB(0);            // 4 loads
  stageB(1);            // 4 loads
  asm volatile("s_waitcnt vmcnt(4)" ::: "memory");  // tile0 landed
  __builtin_amdgcn_s_barrier();

  for (int t = 0; t < NT; ++t) {
    const __bf16* lA = lds + (t & 1) * 24576;
    const __bf16* lB = lA + 8192;

    // ======== P0: f-half 0 ========
    bf16x8 af[2][2], bfr[4][2];
#pragma unroll
    for (int f = 0; f < 2; ++f) {
      const int rowb = (wm * 64 + f * 16 + l16) * 64;
#pragma unroll
      for (int ks = 0; ks < 2; ++ks)
        af[f][ks] = *(const bf16x8*)&lA[rowb + (((ks * 4 + quad) ^ xr) * 8)];
    }
#pragma unroll
    for (int g = 0; g < 4; ++g) {
      const int rowb = (wn * 64 + g * 16 + l16) * 64;
#pragma unroll
      for (int ks = 0; ks < 2; ++ks)
        bfr[g][ks] = *(const bf16x8*)&lB[rowb + (((ks * 4 + quad) ^ xr) * 8)];
    }
    if (t + 1 < NT) stageA((t + 1) & 1);  // A region of other buf is free
    __builtin_amdgcn_s_barrier();
    asm volatile("s_waitcnt lgkmcnt(0)" ::: "memory");
    __builtin_amdgcn_sched_barrier(0);
    __builtin_amdgcn_s_setprio(1);
#pragma unroll
    for (int f = 0; f < 2; ++f)
#pragma unroll
      for (int g = 0; g < 4; ++g) {
        acc[f][g] = __builtin_amdgcn_mfma_f32_16x16x32_bf16(af[f][0], bfr[g][0],
                                                            acc[f][g], 0, 0, 0);
        acc[f][g] = __builtin_amdgcn_mfma_f32_16x16x32_bf16(af[f][1], bfr[g][1],
                                                            acc[f][g], 0, 0, 0);
      }
    __builtin_amdgcn_s_setprio(0);
    __builtin_amdgcn_s_barrier();  // closes B region of buf[t&1]

    // ======== P1: f-half 1 ========
    bf16x8 ah[2][2];
#pragma unroll
    for (int f = 0; f < 2; ++f) {
      const int rowb = (wm * 64 + (f + 2) * 16 + l16) * 64;
#pragma unroll
      for (int ks = 0; ks < 2; ++ks)
        ah[f][ks] = *(const bf16x8*)&lA[rowb + (((ks * 4 + quad) ^ xr) * 8)];
    }
    if (t + 2 < NT) stageB(t & 1);  // B region of buf[t&1] freed by P0 close
    __builtin_amdgcn_s_barrier();
    asm volatile("s_waitcnt lgkmcnt(0)" ::: "memory");
    __builtin_amdgcn_sched_barrier(0);
    __builtin_amdgcn_s_setprio(1);
#pragma unroll
    for (int f = 0; f < 2; ++f)
#pragma unroll
      for (int g = 0; g < 4; ++g) {
        acc[f + 2][g] = __builtin_amdgcn_mfma_f32_16x16x32_bf16(
            ah[f][0], bfr[g][0], acc[f + 2][g], 0, 0, 0);
        acc[f + 2][g] = __builtin_amdgcn_mfma_f32_16x16x32_bf16(
            ah[f][1], bfr[g][1], acc[f + 2][g], 0, 0, 0);
      }
    __builtin_amdgcn_s_setprio(0);

    if (t + 2 < NT) {
      asm volatile("s_waitcnt vmcnt(4)" ::: "memory");
      __builtin_amdgcn_s_barrier();
    } else if (t + 1 < NT) {
      asm volatile("s_waitcnt vmcnt(0)" ::: "memory");
      __builtin_amdgcn_s_barrier();
    }
  }

  // C/D layout: col = lane&15 (n), row = quad*4 + reg (m). [m89/m91]
#pragma unroll
  for (int f = 0; f < 4; ++f) {
#pragma unroll
    for (int g = 0; g < 4; ++g) {
#pragma unroll
      for (int r = 0; r < 4; ++r) {
        const int m = m0 + wm * 64 + f * 16 + quad * 4 + r;
        const int n = n0 + wn * 64 + g * 16 + l16;
        if (epi == 0) Cf[(size_t)m * N + n] = acc[f][g][r];
        else          Cb[(size_t)m * N + n] = (__bf16)acc[f][g][r];
      }
    }
  }
}

// ---------------------------------------------------------------------------
// K/V projection, round 7: bf16 A (pre-converted kb/vb) staged via
// global_load_lds (drops the fp32 VGPR-roundtrip convert), 2D XCD map:
// xcd&1 selects K vs V (own A and B per XCD), xcd>>1 = m-quarter.
// Per-XCD working set: A-quarter 4MB + B 2MB (was: full 16MB fp32 A x8).
// ---------------------------------------------------------------------------
__global__ __launch_bounds__(256, 2) void gemm_kv(
    const __bf16* __restrict__ kb, const __bf16* __restrict__ vb,
    const __bf16* __restrict__ WTk, const __bf16* __restrict__ WTv,
    __bf16* __restrict__ Kp, __bf16* __restrict__ Vt) {
  __shared__ __align__(16) __bf16 As[128 * 32];
  __shared__ __align__(16) __bf16 Bs[128 * 32];

  const int bxl = blockIdx.x;      // 0..255
  const int xcd = bxl & 7;
  const int sub = bxl >> 3;        // 0..31
  const int mat = xcd & 1;         // 0 = K-proj, 1 = V-proj
  const int m0 = ((xcd >> 1) * 8 + (sub >> 2)) * 128;  // 32 m-blocks
  const int n0 = (sub & 3) * 128;                      // 4 n-blocks (N=512)
  const __bf16* A  = mat ? vb : kb;
  const __bf16* Bt = mat ? WTv : WTk;
  const int K = E_;
  const int N = KVDIM;

  const int tid = threadIdx.x;
  const int w = tid >> 6;
  const int lane = tid & 63;
  const int quad = lane >> 4;
  const int l16 = lane & 15;
  const int wr = w >> 1, wc = w & 1;
  const int brow = lane >> 2;
  const int bcol = (lane & 3) * 8;

  f32x4 acc[4][4] = {};

  for (int k0 = 0; k0 < K; k0 += 32) {
    __syncthreads();
#pragma unroll
    for (int c = 0; c < 2; ++c) {
      const int chunk = w * 2 + c;
      const int row = chunk * 16 + brow;
      async_copy16(Bt + (size_t)(n0 + row) * K + k0 + bcol, &Bs[chunk * 512]);
      async_copy16(A + (size_t)(m0 + row) * K + k0 + bcol, &As[chunk * 512]);
    }
    __syncthreads();  // compiler emits vmcnt(0) drain before barrier
    bf16x8 af[4], bfr[4];
#pragma unroll
    for (int i = 0; i < 4; ++i)
      af[i] = *(const bf16x8*)&As[(wr * 64 + i * 16 + l16) * 32 + quad * 8];
#pragma unroll
    for (int j = 0; j < 4; ++j)
      bfr[j] = *(const bf16x8*)&Bs[(wc * 64 + j * 16 + l16) * 32 + quad * 8];
#pragma unroll
    for (int i = 0; i < 4; ++i)
#pragma unroll
      for (int j = 0; j < 4; ++j)
        acc[i][j] = __builtin_amdgcn_mfma_f32_16x16x32_bf16(af[i], bfr[j],
                                                            acc[i][j], 0, 0, 0);
  }

#pragma unroll
  for (int i = 0; i < 4; ++i) {
#pragma unroll
    for (int j = 0; j < 4; ++j) {
#pragma unroll
      for (int r = 0; r < 4; ++r) {
        const int m = m0 + wr * 64 + i * 16 + quad * 4 + r;
        const int n = n0 + wc * 64 + j * 16 + l16;
        if (mat == 0) {
          Kp[(size_t)m * N + n] = (__bf16)acc[i][j][r];
        } else {
          const int b = m >> 11, s = m & (S_ - 1);
          Vt[((size_t)((b * HKV_ + (n >> 7)) * D_ + (n & (D_ - 1)))) * S_ + s] =
              (__bf16)acc[i][j][r];
        }
      }
    }
  }
}

// ---------------------------------------------------------------------------
// Flash attention: round-4 version verbatim (best measured: 104.7 us).
// T14 async-STAGE split; no P swizzle (round-5/6 attn experiments reverted).
// ---------------------------------------------------------------------------
__global__ __launch_bounds__(256, 2) void attn_kernel(
    const __bf16* __restrict__ Q, const __bf16* __restrict__ Kp,
    const __bf16* __restrict__ Vt, const float* __restrict__ mask,
    __bf16* __restrict__ Oa) {
  __shared__ __align__(16) __bf16 K_lds[64][136];
  __shared__ __align__(16) __bf16 V_lds[128][72];
  __shared__ __align__(16) __bf16 P_lds[4][32][72];

  const int tid = threadIdx.x;
  const int w = tid >> 6, lane = tid & 63, quad = lane >> 4, l16 = lane & 15;
  const int bh = blockIdx.y;
  const int b = bh >> 4, h = bh & 15, hkv = h >> 2;
  const int q0 = blockIdx.x * 128 + w * 32;

  const __bf16* qbase = Q + (size_t)(b * S_ + q0) * E_ + h * D_;
  bf16x8 qf[2][4];
#pragma unroll
  for (int m = 0; m < 2; ++m)
#pragma unroll
    for (int ks = 0; ks < 4; ++ks)
      qf[m][ks] = *(const bf16x8*)(qbase + (size_t)(m * 16 + l16) * E_ +
                                   ks * 32 + quad * 8);

  const __bf16* kbase = Kp + (size_t)(b * S_) * KVDIM + hkv * D_;
  const __bf16* vbase = Vt + (size_t)((b * HKV_ + hkv) * D_) * S_;
  const float* mbase = mask + b * S_;

  // Staging geometry (T14 split issue/write):
  const int kr = w * 16 + (lane >> 4);        // K row base (+i*4)
  const int kc = (lane & 15) * 8;             // K col
  const int vr = w * 32 + (lane >> 3);        // V row base (+i*8)
  const int vc = (lane & 7) * 8;              // V col (within kt tile)

  bf16x8 kreg[4], vreg[4];
  auto fetch = [&](int kt) {
#pragma unroll
    for (int i = 0; i < 4; ++i)
      kreg[i] = *(const bf16x8*)(kbase + (size_t)(kt + kr + i * 4) * KVDIM + kc);
#pragma unroll
    for (int i = 0; i < 4; ++i)
      vreg[i] = *(const bf16x8*)(vbase + (size_t)(vr + i * 8) * S_ + kt + vc);
  };

  f32x4 o[2][8] = {};
  f32x4 lsum[2] = {};
  const float scale = 0.08838834764831845f;  // 1/sqrt(128)

  fetch(0);  // prologue prefetch

  for (int kt = 0; kt < S_; kt += 64) {
    // write current tile's regs -> LDS (prev iter's read-sync guarantees safe)
#pragma unroll
    for (int i = 0; i < 4; ++i)
      *(bf16x8*)&K_lds[kr + i * 4][kc] = kreg[i];
#pragma unroll
    for (int i = 0; i < 4; ++i)
      *(bf16x8*)&V_lds[vr + i * 8][vc] = vreg[i];
    __syncthreads();  // LDS(t) visible to all

    // T14: issue next tile's global loads NOW — hidden under compute below
    if (kt + 64 < S_) fetch(kt + 64);

    f32x4 s[2][4] = {};
    __builtin_amdgcn_s_setprio(1);
#pragma unroll
    for (int ks = 0; ks < 4; ++ks) {
#pragma unroll
      for (int n = 0; n < 4; ++n) {
        bf16x8 kf = *(const bf16x8*)&K_lds[n * 16 + l16][ks * 32 + quad * 8];
        s[0][n] = __builtin_amdgcn_mfma_f32_16x16x32_bf16(qf[0][ks], kf,
                                                          s[0][n], 0, 0, 0);
        s[1][n] = __builtin_amdgcn_mfma_f32_16x16x32_bf16(qf[1][ks], kf,
                                                          s[1][n], 0, 0, 0);
      }
    }
    __builtin_amdgcn_s_setprio(0);

    float bias[4];
#pragma unroll
    for (int n = 0; n < 4; ++n)
      bias[n] = (1.0f - mbase[kt + n * 16 + l16]) * -1e9f;
#pragma unroll
    for (int m = 0; m < 2; ++m) {
#pragma unroll
      for (int n = 0; n < 4; ++n) {
#pragma unroll
        for (int r = 0; r < 4; ++r) {
          const float p = __expf(s[m][n][r] * scale + bias[n]);
          lsum[m][r] += p;
          P_lds[w][m * 16 + quad * 4 + r][n * 16 + l16] = (__bf16)p;
        }
      }
    }

    __builtin_amdgcn_s_setprio(1);
#pragma unroll
    for (int ks2 = 0; ks2 < 2; ++ks2) {
      bf16x8 pa[2];
#pragma unroll
      for (int m = 0; m < 2; ++m)
        pa[m] = *(const bf16x8*)&P_lds[w][m * 16 + l16][ks2 * 32 + quad * 8];
#pragma unroll
      for (int dt = 0; dt < 8; ++dt) {
        bf16x8 vf = *(const bf16x8*)&V_lds[dt * 16 + l16][ks2 * 32 + quad * 8];
        o[0][dt] = __builtin_amdgcn_mfma_f32_16x16x32_bf16(pa[0], vf,
                                                           o[0][dt], 0, 0, 0);
        o[1][dt] = __builtin_amdgcn_mfma_f32_16x16x32_bf16(pa[1], vf,
                                                           o[1][dt], 0, 0, 0);
      }
    }
    __builtin_amdgcn_s_setprio(0);

    __syncthreads();  // all reads of LDS(t) done -> next iter may overwrite
  }

  __bf16* obase = Oa + (size_t)(b * S_ + q0) * E_ + h * D_;
#pragma unroll
  for (int m = 0; m < 2; ++m) {
#pragma unroll
    for (int r = 0; r < 4; ++r) {
      float v = lsum[m][r];
#pragma unroll
      for (int off = 1; off < 16; off <<= 1) v += __shfl_xor(v, off);
      const float inv = 1.0f / v;
#pragma unroll
      for (int dt = 0; dt < 8; ++dt)
        obase[(size_t)(m * 16 + quad * 4 + r) * E_ + dt * 16 + l16] =
            (__bf16)(o[m][dt][r] * inv);
    }
  }
}

// ---------------------------------------------------------------------------
extern "C" void kernel_launch(void* const* d_in, const int* in_sizes, int n_in,
                              void* d_out, int out_size, void* d_ws,
                              size_t ws_size, hipStream_t stream) {
  const float* query = (const float*)d_in[0];
  const float* key   = (const float*)d_in[1];
  const float* value = (const float*)d_in[2];
  const float* mask  = (const float*)d_in[3];
  const float* Wq    = (const float*)d_in[4];
  const float* Wk    = (const float*)d_in[5];
  const float* Wv    = (const float*)d_in[6];
  const float* Wo    = (const float*)d_in[7];
  float* out = (float*)d_out;

  // Workspace 48 MB (known-safe), bf16 elements:
  //   Qp 16MB | Kp 4MB | Vt 4MB | WoT 8MB | WTq 8MB | WTk 2MB | WTv 2MB | sp
  // Attn (16MB) overlaps [WTq|WTk|WTv|spare] — consumed before attention runs.
  // d_out (32MB fp32) doubles as bf16 scratch: qb @0 (16MB) + kb @16MB (16MB)
  // — both consumed before gemm_o writes d_out.
  // vb (16MB) lives in the Qp slot — consumed by gemm_kv BEFORE the Q-pipe
  // writes Qp (stream-serialized).
  __bf16* ws   = (__bf16*)d_ws;
  __bf16* Qp   = ws;                           // @ 0
  __bf16* Kp   = Qp + (size_t)NTOK * E_;       // @ 16MB
  __bf16* Vt   = Kp + (size_t)NTOK * KVDIM;    // @ 20MB
  __bf16* WoT  = Vt + (size_t)NTOK * KVDIM;    // @ 24MB
  __bf16* WTq  = WoT + (size_t)E_ * E_;        // @ 32MB
  __bf16* WTk  = WTq + (size_t)E_ * E_;        // @ 40MB
  __bf16* WTv  = WTk + (size_t)KVDIM * E_;     // @ 42MB
  __bf16* Attn = WTq;                          // @ 32MB (16MB, reuse)
  __bf16* qb   = (__bf16*)d_out;               // d_out @ 0
  __bf16* kb   = qb + (size_t)NTOK * E_;       // d_out @ 16MB
  __bf16* vb   = Qp;                           // ws @ 0 (before Qp written)

  // 1) weight transposes + q/k/v fp32->bf16 converts, one launch (z=0..6)
  transpose_all<<<dim3(64, 32, 7), 256, 0, stream>>>(
      Wq, Wk, Wv, Wo, WTq, WTk, WTv, WoT, query, key, value, qb, kb, vb);
  // 2) K/V projections (bf16 A, async staging, 2D XCD map), 256 blocks
  gemm_kv<<<dim3(256), 256, 0, stream>>>(kb, vb, WTk, WTv, Kp, Vt);
  // 3) Q projection via pipelined GEMM (2D XCD map): qb @ WTq -> Qp
  gemm_pipe<<<dim3(256), 512, 0, stream>>>(
      qb, WTq, nullptr, Qp, NTOK, E_, E_, 1);
  // 4) attention -> Attn (clobbers WTq/k/v, already consumed)
  attn_kernel<<<dim3(S_ / 128, B_ * H_), 256, 0, stream>>>(Qp, Kp, Vt, mask,
                                                           Attn);
  // 5) output projection via pipelined GEMM (fp32 epilogue straight to d_out)
  gemm_pipe<<<dim3(256), 512, 0, stream>>>(
      Attn, WoT, out, nullptr, NTOK, E_, E_, 0);
}